// Round 10
// baseline (372.724 us; speedup 1.0000x reference)
//
#include <hip/hip_runtime.h>
#include <hip/hip_bf16.h>

#define BATCH 8
#define SEQ   2048
#define DIM   512
#define QB    32
#define KB    64
#define NT    512          // 8 waves
#define NKV   (SEQ / KB)   // 32 KV tiles

typedef __attribute__((ext_vector_type(8))) short short8;
typedef __attribute__((ext_vector_type(4))) float f32x4;
typedef __attribute__((ext_vector_type(4))) unsigned short ushort4v;

__device__ __forceinline__ unsigned short f2bf(float f) {
    union { float f; unsigned u; } v; v.f = f;
    return (unsigned short)((v.u + 0x7FFFu + ((v.u >> 16) & 1u)) >> 16);
}

// ---- pre-pass: X fp32 -> Xbf (row-major bf16) + Xt (transposed bf16 [b][d][s])
__global__ __launch_bounds__(256)
void prep_kernel(const float* __restrict__ X,
                 unsigned short* __restrict__ Xbf,
                 unsigned short* __restrict__ Xt) {
    __shared__ unsigned short T[64][72];   // [s][d], padded
    const int b  = blockIdx.z;
    const int s0 = blockIdx.x * 64;
    const int d0 = blockIdx.y * 64;
    const int tid = threadIdx.x;
    const float* Xb = X + ((size_t)b * SEQ + s0) * DIM + d0;
    unsigned short* Yb = Xbf + ((size_t)b * SEQ + s0) * DIM + d0;
    #pragma unroll
    for (int r = 0; r < 4; ++r) {
        const int s = (tid >> 4) + r * 16;
        const int d = (tid & 15) * 4;
        float4 v = *(const float4*)(Xb + (size_t)s * DIM + d);
        ushort4v h;
        h[0] = f2bf(v.x); h[1] = f2bf(v.y); h[2] = f2bf(v.z); h[3] = f2bf(v.w);
        *(ushort4v*)(Yb + (size_t)s * DIM + d) = h;
        *(ushort4v*)&T[s][d] = h;
    }
    __syncthreads();
    {
        const int d = tid >> 2;
        const int sc = (tid & 3) * 16;
        unsigned short buf[16];
        #pragma unroll
        for (int j = 0; j < 16; ++j) buf[j] = T[sc + j][d];
        unsigned short* o = Xt + ((size_t)b * DIM + d0 + d) * SEQ + s0 + sc;
        *(short8*)(o)     = *(short8*)&buf[0];
        *(short8*)(o + 8) = *(short8*)&buf[8];
    }
}

// Async DMA stage of V^T tile t from Xt into vtlds[d][kv] (kv ^= 8*(d&7)).
// Linear dest + inverse-swizzled per-lane source (validated R9).
__device__ __forceinline__ void stage_V(const unsigned short* __restrict__ Xtb,
                                        unsigned short* vtlds, int t, int w, int lane) {
    #pragma unroll
    for (int k = 0; k < 8; ++k) {
        const int r = w * 64 + k * 8 + (lane >> 3);          // absolute d-row
        const int kvsrc = ((lane & 7) * 8) ^ (8 * (r & 7));  // involution
        const unsigned short* g = Xtb + (size_t)r * SEQ + t * KB + kvsrc;
        unsigned short* l = vtlds + (w * 64 + k * 8) * KB;   // wave-uniform base
        __builtin_amdgcn_global_load_lds(
            (__attribute__((address_space(1))) void*)(g),
            (__attribute__((address_space(3))) void*)(l), 16, 0, 0);
    }
}

// score = X·X^T (no scaling), softmax, out = P·X — flash-style, bf16 MFMA.
// K is NOT staged in LDS: QK B-fragments are row-contiguous 16B reads served
// by L1/L2 (per-batch X is L2-resident with XCD pinning). Freed LDS double-
// buffers V^T so the DMA wait lands at end-of-iter, hidden under compute (R8).
__global__ __launch_bounds__(NT, 2)
void attn_fwd(const unsigned short* __restrict__ Xbf,
              const unsigned short* __restrict__ Xt,
              float* __restrict__ O) {
    const int b   = blockIdx.x & 7;          // batch -> XCD pinning
    const int qt  = blockIdx.x >> 3;         // 0..63
    const int tid = threadIdx.x;
    const int lane = tid & 63;
    const int w    = tid >> 6;
    const int col  = lane & 15;
    const int kgrp = lane >> 4;

    __shared__ alignas(16) unsigned short Vtlds[2][DIM * KB];   // 128 KB dbuf
    __shared__ alignas(16) float Sbuf[QB][KB + 4];              // 8.7 KB
    __shared__ alignas(16) unsigned short Pfrag[2][2][64][8];   // 4 KB
    __shared__ float m_s[QB], l_s[QB], fac_s[QB];

    const unsigned short* Xb  = Xbf + (size_t)b * SEQ * DIM;
    const unsigned short* Xtb = Xt  + (size_t)b * DIM * SEQ;

    // ---- Q preload: wave w owns 16 q-rows (strip qs = w>>2), kc strip = w&3
    const int qs = w >> 2;       // 0..1
    const int kc = w & 3;        // 0..3
    short8 qfrag[16];            // 64 VGPR
    {
        const int qrow = qt * QB + qs * 16 + col;
        const unsigned short* qp = Xb + (size_t)qrow * DIM;
        #pragma unroll
        for (int ks = 0; ks < 16; ++ks)
            qfrag[ks] = *(const short8*)(qp + ks * 32 + kgrp * 8);
    }

    if (tid < QB) { m_s[tid] = -INFINITY; l_s[tid] = 0.f; }

    f32x4 oacc[2][4];   // O[32 q][w*64 .. +64 d] : [q2][dt]
    #pragma unroll
    for (int i = 0; i < 2; ++i)
        #pragma unroll
        for (int j = 0; j < 4; ++j)
            oacc[i][j] = (f32x4){0.f, 0.f, 0.f, 0.f};

    // ---- prologue: stage V^T tile 0 -> buf 0
    stage_V(Xtb, &Vtlds[0][0], 0, w, lane);
    asm volatile("s_waitcnt vmcnt(0)" ::: "memory");
    __syncthreads();   // tile 0 ready (also covers qfrag)

    for (int t = 0; t < NKV; ++t) {
        const int cur = t & 1;
        // issue next V^T tile's DMA; lands under this iter's compute
        if (t + 1 < NKV) stage_V(Xtb, &Vtlds[cur ^ 1][0], t + 1, w, lane);

        // ---- QK^T from GLOBAL: wave computes S[qs*16 .. +16][kc*16 .. +16]
        {
            const unsigned short* krow = Xb + (size_t)(t * KB + kc * 16 + col) * DIM;
            f32x4 sacc = (f32x4){0.f,0.f,0.f,0.f};
            #pragma unroll
            for (int ks = 0; ks < 16; ++ks) {
                short8 kfr = *(const short8*)(krow + ks * 32 + kgrp * 8);
                sacc = __builtin_amdgcn_mfma_f32_16x16x32_bf16(qfrag[ks], kfr, sacc, 0, 0, 0);
            }
            #pragma unroll
            for (int r = 0; r < 4; ++r)
                Sbuf[qs * 16 + kgrp * 4 + r][kc * 16 + col] = sacc[r];
        }
        __syncthreads();   // (B) Sbuf ready

        // ---- online softmax: 16 threads/row, 4 scores each
        {
            const int r = tid >> 4;     // 0..31
            const int c = tid & 15;     // 0..15
            float4 sa = *(const float4*)&Sbuf[r][c * 4];
            float mloc = fmaxf(fmaxf(sa.x, sa.y), fmaxf(sa.z, sa.w));
            mloc = fmaxf(mloc, __shfl_xor(mloc, 1));
            mloc = fmaxf(mloc, __shfl_xor(mloc, 2));
            mloc = fmaxf(mloc, __shfl_xor(mloc, 4));
            mloc = fmaxf(mloc, __shfl_xor(mloc, 8));
            const float mold = m_s[r];
            const float mnew = fmaxf(mold, mloc);
            const float fac  = __expf(mold - mnew);   // exp(-inf)=0 on first tile
            float p0 = __expf(sa.x - mnew), p1 = __expf(sa.y - mnew);
            float p2 = __expf(sa.z - mnew), p3 = __expf(sa.w - mnew);
            float lsum = (p0 + p1) + (p2 + p3);
            lsum += __shfl_xor(lsum, 1);
            lsum += __shfl_xor(lsum, 2);
            lsum += __shfl_xor(lsum, 4);
            lsum += __shfl_xor(lsum, 8);
            ushort4v p4;
            p4[0] = f2bf(p0); p4[1] = f2bf(p1); p4[2] = f2bf(p2); p4[3] = f2bf(p3);
            // value (q=r, kv=4c+jj) -> Pfrag[q>>4][kv>>5][(q&15)+16*((kv>>3)&3)][kv&7]
            *(ushort4v*)&Pfrag[r >> 4][c >> 3][(r & 15) + 16 * ((c >> 1) & 3)][(c & 1) * 4] = p4;
            if (c == 0) {
                m_s[r] = mnew;
                fac_s[r] = fac;
                l_s[r] = l_s[r] * fac + lsum;
            }
        }
        __syncthreads();   // (C) Pfrag/fac ready

        // ---- rescale O, then PV: A from Pfrag, B from Vtlds[cur] (both b128)
        #pragma unroll
        for (int q2 = 0; q2 < 2; ++q2) {
            #pragma unroll
            for (int r = 0; r < 4; ++r) {
                const float f = fac_s[q2 * 16 + kgrp * 4 + r];
                #pragma unroll
                for (int dt = 0; dt < 4; ++dt) oacc[q2][dt][r] *= f;
            }
        }
        #pragma unroll
        for (int kc2 = 0; kc2 < 2; ++kc2) {
            const int kvb = kc2 * 32 + kgrp * 8;
            short8 afr[2];
            #pragma unroll
            for (int q2 = 0; q2 < 2; ++q2)
                afr[q2] = *(const short8*)&Pfrag[q2][kc2][lane][0];
            #pragma unroll
            for (int dt = 0; dt < 4; ++dt) {
                const int d = w * 64 + dt * 16 + col;
                const short8 bfr = *(const short8*)&Vtlds[cur][d * KB + (kvb ^ (8 * (d & 7)))];
                #pragma unroll
                for (int q2 = 0; q2 < 2; ++q2)
                    oacc[q2][dt] = __builtin_amdgcn_mfma_f32_16x16x32_bf16(afr[q2], bfr, oacc[q2][dt], 0, 0, 0);
            }
        }

        // ---- end of iter: next tile's DMA landed; all waves done with cur
        asm volatile("s_waitcnt vmcnt(0)" ::: "memory");
        __syncthreads();   // (A)
    }

    // ---- epilogue: divide by l, store fp32
    #pragma unroll
    for (int q2 = 0; q2 < 2; ++q2) {
        #pragma unroll
        for (int r = 0; r < 4; ++r) {
            const int row = q2 * 16 + kgrp * 4 + r;
            const float inv = 1.f / l_s[row];
            float* op = O + ((size_t)b * SEQ + qt * QB + row) * DIM + w * 64 + col;
            #pragma unroll
            for (int dt = 0; dt < 4; ++dt)
                op[dt * 16] = oacc[q2][dt][r] * inv;
        }
    }
}

extern "C" void kernel_launch(void* const* d_in, const int* in_sizes, int n_in,
                              void* d_out, int out_size, void* d_ws, size_t ws_size,
                              hipStream_t stream) {
    const float* X = (const float*)d_in[0];
    float* Out = (float*)d_out;
    unsigned short* Xbf = (unsigned short*)d_ws;                       // 16.8 MB
    unsigned short* Xt  = Xbf + (size_t)BATCH * SEQ * DIM;             // 16.8 MB

    dim3 pgrid(SEQ / 64, DIM / 64, BATCH);   // 32 x 8 x 8
    hipLaunchKernelGGL(prep_kernel, pgrid, dim3(256), 0, stream, X, Xbf, Xt);

    dim3 grid(BATCH * (SEQ / QB));           // 512 blocks
    dim3 block(NT);
    hipLaunchKernelGGL(attn_fwd, grid, block, 0, stream, Xbf, Xt, Out);
}

// Round 11
// 196.049 us; speedup vs baseline: 1.9012x; 1.9012x over previous
//
#include <hip/hip_runtime.h>
#include <hip/hip_bf16.h>

#define BATCH 8
#define SEQ   2048
#define DIM   512
#define QB    32
#define KB    64
#define NT    512          // 8 waves
#define NKV   (SEQ / KB)   // 32 KV tiles

typedef __attribute__((ext_vector_type(8))) short short8;
typedef __attribute__((ext_vector_type(4))) float f32x4;
typedef __attribute__((ext_vector_type(4))) unsigned short ushort4v;

__device__ __forceinline__ unsigned short f2bf(float f) {
    union { float f; unsigned u; } v; v.f = f;
    return (unsigned short)((v.u + 0x7FFFu + ((v.u >> 16) & 1u)) >> 16);
}

// K-tile row swizzle (validated R4-R9).
__device__ __forceinline__ int swz(int kv) {
    return (8 * (kv & 7)) ^ (16 * ((kv >> 3) & 3)) ^ (64 * ((kv >> 3) & 1));
}

// ---- pre-pass: X fp32 -> Xbf (row-major bf16) + Xt (transposed bf16 [b][d][s])
__global__ __launch_bounds__(256)
void prep_kernel(const float* __restrict__ X,
                 unsigned short* __restrict__ Xbf,
                 unsigned short* __restrict__ Xt) {
    __shared__ unsigned short T[64][72];   // [s][d], padded
    const int b  = blockIdx.z;
    const int s0 = blockIdx.x * 64;
    const int d0 = blockIdx.y * 64;
    const int tid = threadIdx.x;
    const float* Xb = X + ((size_t)b * SEQ + s0) * DIM + d0;
    unsigned short* Yb = Xbf + ((size_t)b * SEQ + s0) * DIM + d0;
    #pragma unroll
    for (int r = 0; r < 4; ++r) {
        const int s = (tid >> 4) + r * 16;
        const int d = (tid & 15) * 4;
        float4 v = *(const float4*)(Xb + (size_t)s * DIM + d);
        ushort4v h;
        h[0] = f2bf(v.x); h[1] = f2bf(v.y); h[2] = f2bf(v.z); h[3] = f2bf(v.w);
        *(ushort4v*)(Yb + (size_t)s * DIM + d) = h;
        *(ushort4v*)&T[s][d] = h;
    }
    __syncthreads();
    {
        const int d = tid >> 2;
        const int sc = (tid & 3) * 16;
        unsigned short buf[16];
        #pragma unroll
        for (int j = 0; j < 16; ++j) buf[j] = T[sc + j][d];
        unsigned short* o = Xt + ((size_t)b * DIM + d0 + d) * SEQ + s0 + sc;
        *(short8*)(o)     = *(short8*)&buf[0];
        *(short8*)(o + 8) = *(short8*)&buf[8];
    }
}

// Async DMA stage of K tile t (linear dest, pre-swizzled src). 8 instr/thread.
__device__ __forceinline__ void stage_K(const unsigned short* __restrict__ Xb,
                                        unsigned short* klds, int t, int w, int lane) {
    const unsigned short* kp = Xb + (size_t)(t * KB) * DIM;
    #pragma unroll
    for (int k = 0; k < 8; ++k) {
        const int kv = k * 8 + w;
        const int dsrc = (lane * 8) ^ swz(kv);
        const unsigned short* g = kp + (size_t)kv * DIM + dsrc;
        unsigned short* l = klds + kv * DIM;
        __builtin_amdgcn_global_load_lds(
            (__attribute__((address_space(1))) void*)(g),
            (__attribute__((address_space(3))) void*)(l), 16, 0, 0);
    }
}

// Async DMA stage of V^T tile t into vtlds[d][kv] (kv ^= 8*(d&7)). 8 instr/thread.
__device__ __forceinline__ void stage_V(const unsigned short* __restrict__ Xtb,
                                        unsigned short* vtlds, int t, int w, int lane) {
    #pragma unroll
    for (int k = 0; k < 8; ++k) {
        const int r = w * 64 + k * 8 + (lane >> 3);          // absolute d-row
        const int kvsrc = ((lane & 7) * 8) ^ (8 * (r & 7));  // involution
        const unsigned short* g = Xtb + (size_t)r * SEQ + t * KB + kvsrc;
        unsigned short* l = vtlds + (w * 64 + k * 8) * KB;   // wave-uniform base
        __builtin_amdgcn_global_load_lds(
            (__attribute__((address_space(1))) void*)(g),
            (__attribute__((address_space(3))) void*)(l), 16, 0, 0);
    }
}

// score = X·X^T (no scaling), softmax, out = P·X — flash-style, bf16 MFMA.
// Single-buffered K and V^T; latency hidden by issuing each tile's DMA in the
// phase where its buffer is dead and draining with COUNTED vmcnt(8) (T4):
//   B: Klds dead -> issue K(t+1);  C: vmcnt(8) drains V(t), K(t+1) flies
//   D: Vt dead   -> issue V(t+1);  A: vmcnt(8) drains K(t+1), V(t+1) flies
__global__ __launch_bounds__(NT, 2)
void attn_fwd(const unsigned short* __restrict__ Xbf,
              const unsigned short* __restrict__ Xt,
              float* __restrict__ O) {
    const int b   = blockIdx.x & 7;          // batch -> XCD pinning
    const int qt  = blockIdx.x >> 3;         // 0..63
    const int tid = threadIdx.x;
    const int lane = tid & 63;
    const int w    = tid >> 6;
    const int col  = lane & 15;
    const int kgrp = lane >> 4;

    __shared__ alignas(16) unsigned short Klds[KB * DIM];       // 64 KB
    __shared__ alignas(16) unsigned short Vtlds[DIM * KB];      // 64 KB
    __shared__ alignas(16) float Sbuf[QB][KB + 4];              // 8.7 KB
    __shared__ alignas(16) unsigned short Pfrag[2][2][64][8];   // 4 KB
    __shared__ float m_s[QB], l_s[QB], fac_s[QB];

    const unsigned short* Xb  = Xbf + (size_t)b * SEQ * DIM;
    const unsigned short* Xtb = Xt  + (size_t)b * DIM * SEQ;

    // ---- Q preload: wave w owns 16 q-rows (strip qs = w>>2), kc strip = w&3
    const int qs = w >> 2;       // 0..1
    const int kc = w & 3;        // 0..3
    short8 qfrag[16];            // 64 VGPR
    {
        const int qrow = qt * QB + qs * 16 + col;
        const unsigned short* qp = Xb + (size_t)qrow * DIM;
        #pragma unroll
        for (int ks = 0; ks < 16; ++ks)
            qfrag[ks] = *(const short8*)(qp + ks * 32 + kgrp * 8);
    }

    if (tid < QB) { m_s[tid] = -INFINITY; l_s[tid] = 0.f; }

    f32x4 oacc[2][4];   // O[32 q][w*64 .. +64 d] : [q2][dt]
    #pragma unroll
    for (int i = 0; i < 2; ++i)
        #pragma unroll
        for (int j = 0; j < 4; ++j)
            oacc[i][j] = (f32x4){0.f, 0.f, 0.f, 0.f};

    // ---- prologue: stage tile 0 (both), full drain once
    stage_K(Xb,  Klds,  0, w, lane);
    stage_V(Xtb, Vtlds, 0, w, lane);
    asm volatile("s_waitcnt vmcnt(0)" ::: "memory");
    __syncthreads();   // tile 0 ready (also covers qfrag loads)

    for (int t = 0; t < NKV; ++t) {
        // ---- QK^T: wave computes S[qs*16 .. +16][kc*16 .. +16]
        {
            const int kvrow = kc * 16 + col;
            const unsigned short* kbase = &Klds[kvrow * DIM];
            const int sw = swz(kvrow);
            f32x4 sacc = (f32x4){0.f,0.f,0.f,0.f};
            #pragma unroll
            for (int ks = 0; ks < 16; ++ks) {
                short8 kfr = *(const short8*)(kbase + ((ks * 32 + kgrp * 8) ^ sw));
                sacc = __builtin_amdgcn_mfma_f32_16x16x32_bf16(qfrag[ks], kfr, sacc, 0, 0, 0);
            }
            #pragma unroll
            for (int r = 0; r < 4; ++r)
                Sbuf[qs * 16 + kgrp * 4 + r][kc * 16 + col] = sacc[r];
        }
        __syncthreads();   // (B) Sbuf ready + Klds dead

        // issue next K tile into the (dead) single K buffer
        if (t + 1 < NKV) stage_K(Xb, Klds, t + 1, w, lane);

        // ---- online softmax: 16 threads/row, 4 scores each
        {
            const int r = tid >> 4;     // 0..31
            const int c = tid & 15;     // 0..15
            float4 sa = *(const float4*)&Sbuf[r][c * 4];
            float mloc = fmaxf(fmaxf(sa.x, sa.y), fmaxf(sa.z, sa.w));
            mloc = fmaxf(mloc, __shfl_xor(mloc, 1));
            mloc = fmaxf(mloc, __shfl_xor(mloc, 2));
            mloc = fmaxf(mloc, __shfl_xor(mloc, 4));
            mloc = fmaxf(mloc, __shfl_xor(mloc, 8));
            const float mold = m_s[r];
            const float mnew = fmaxf(mold, mloc);
            const float fac  = __expf(mold - mnew);   // exp(-inf)=0 on first tile
            float p0 = __expf(sa.x - mnew), p1 = __expf(sa.y - mnew);
            float p2 = __expf(sa.z - mnew), p3 = __expf(sa.w - mnew);
            float lsum = (p0 + p1) + (p2 + p3);
            lsum += __shfl_xor(lsum, 1);
            lsum += __shfl_xor(lsum, 2);
            lsum += __shfl_xor(lsum, 4);
            lsum += __shfl_xor(lsum, 8);
            ushort4v p4;
            p4[0] = f2bf(p0); p4[1] = f2bf(p1); p4[2] = f2bf(p2); p4[3] = f2bf(p3);
            *(ushort4v*)&Pfrag[r >> 4][c >> 3][(r & 15) + 16 * ((c >> 1) & 3)][(c & 1) * 4] = p4;
            if (c == 0) {
                m_s[r] = mnew;
                fac_s[r] = fac;
                l_s[r] = l_s[r] * fac + lsum;
            }
        }
        // drain own V(t) DMAs (8 oldest); K(t+1)'s 8 stay in flight
        if (t + 1 < NKV) { asm volatile("s_waitcnt vmcnt(8)" ::: "memory"); }
        else             { asm volatile("s_waitcnt vmcnt(0)" ::: "memory"); }
        __syncthreads();   // (C) Pfrag ready + V(t) published

        // ---- rescale O, then PV: A from Pfrag, B from Vtlds (both b128)
        #pragma unroll
        for (int q2 = 0; q2 < 2; ++q2) {
            #pragma unroll
            for (int r = 0; r < 4; ++r) {
                const float f = fac_s[q2 * 16 + kgrp * 4 + r];
                #pragma unroll
                for (int dt = 0; dt < 4; ++dt) oacc[q2][dt][r] *= f;
            }
        }
        #pragma unroll
        for (int kc2 = 0; kc2 < 2; ++kc2) {
            const int kvb = kc2 * 32 + kgrp * 8;
            short8 afr[2];
            #pragma unroll
            for (int q2 = 0; q2 < 2; ++q2)
                afr[q2] = *(const short8*)&Pfrag[q2][kc2][lane][0];
            #pragma unroll
            for (int dt = 0; dt < 4; ++dt) {
                const int d = w * 64 + dt * 16 + col;
                const short8 bfr = *(const short8*)&Vtlds[d * KB + (kvb ^ (8 * (d & 7)))];
                #pragma unroll
                for (int q2 = 0; q2 < 2; ++q2)
                    oacc[q2][dt] = __builtin_amdgcn_mfma_f32_16x16x32_bf16(afr[q2], bfr, oacc[q2][dt], 0, 0, 0);
            }
        }
        __syncthreads();   // (D) Vtlds dead

        if (t + 1 < NKV) {
            stage_V(Xtb, Vtlds, t + 1, w, lane);     // fills dead V buffer
            asm volatile("s_waitcnt vmcnt(8)" ::: "memory");  // drains K(t+1)
            __syncthreads();   // (A) K(t+1) published; V(t+1) flies under QK
        }
    }

    // ---- epilogue: divide by l, store fp32
    #pragma unroll
    for (int q2 = 0; q2 < 2; ++q2) {
        #pragma unroll
        for (int r = 0; r < 4; ++r) {
            const int row = q2 * 16 + kgrp * 4 + r;
            const float inv = 1.f / l_s[row];
            float* op = O + ((size_t)b * SEQ + qt * QB + row) * DIM + w * 64 + col;
            #pragma unroll
            for (int dt = 0; dt < 4; ++dt)
                op[dt * 16] = oacc[q2][dt][r] * inv;
        }
    }
}

extern "C" void kernel_launch(void* const* d_in, const int* in_sizes, int n_in,
                              void* d_out, int out_size, void* d_ws, size_t ws_size,
                              hipStream_t stream) {
    const float* X = (const float*)d_in[0];
    float* Out = (float*)d_out;
    unsigned short* Xbf = (unsigned short*)d_ws;                       // 16.8 MB
    unsigned short* Xt  = Xbf + (size_t)BATCH * SEQ * DIM;             // 16.8 MB

    dim3 pgrid(SEQ / 64, DIM / 64, BATCH);   // 32 x 8 x 8
    hipLaunchKernelGGL(prep_kernel, pgrid, dim3(256), 0, stream, X, Xbf, Xt);

    dim3 grid(BATCH * (SEQ / QB));           // 512 blocks
    dim3 block(NT);
    hipLaunchKernelGGL(attn_fwd, grid, block, 0, stream, Xbf, Xt, Out);
}